// Round 16
// baseline (226.199 us; speedup 1.0000x reference)
//
#include <hip/hip_runtime.h>
#include <float.h>
#include <math.h>

// ---------------------------------------------------------------------------
// GCN forward, bf16 intermediates, fused register-light tails, 8-lane gather:
//   hs1 = dinv*(x W1) [bf16, gemm1]
//   agg_gemm: h1 = relu(dinv*S(hs1)+b1) -> per-wave LDS -> hs2 = dinv*(h1 W2)
//   agg_head: h2 = relu(dinv*S(hs2)+b2) -> per-wave LDS -> logits -> mask
// Ahat = D^-1/2 (A+I) D^-1/2.  CSR by scan-based counting sort (atomic-free).
// Established facts:
//   - edge_index int32, d_out float32, masked slots need bf16-finite value
//     (-3.3895e38 = bf16 0xFF7F; expected's -3.4028e38 is -inf in bf16).
//   - R4 atomics / R7 random 4B writes / R8 run regather: all bad.
//   - R9/R10: gather at random-128B fabric ceiling only at high occupancy.
//   - R12: VGPR>64 halves waves/SIMD -> gather BW collapses.
//   - R13/R15 (224us best): per-wave LDS tails, 36 VGPR, CHUNK=4096.
//   - R14 REGRESSED: bf16-W2 tail (VALU cvt) + perm indirection (locality).
//   - This round: 8 lanes/node + uint4 loads (was 16 lanes + ushort4):
//     per-edge wave-inst cost ~5.3 -> ~3.3, 2x data in flight per load inst.
// ---------------------------------------------------------------------------

#define MASKED_VAL (-3.3895313892515355e+38f)
#define SHIFT 7
#define BNODES 128   // 1<<SHIFT nodes per bucket
#define CHUNK 4096   // edges per chunk
#define DCAP 6144    // per-bucket region capacity (mean 4096, >30 sigma)
#define NBP 800      // padded row stride for hist/cbbase matrices

typedef unsigned short u16;

static __device__ __forceinline__ float bf2f(u16 u) {
  union { unsigned int i; float f; } x;
  x.i = ((unsigned int)u) << 16;
  return x.f;
}
static __device__ __forceinline__ float lo2f(unsigned int u) {
  union { unsigned int i; float f; } x;
  x.i = u << 16;
  return x.f;
}
static __device__ __forceinline__ float hi2f(unsigned int u) {
  union { unsigned int i; float f; } x;
  x.i = u & 0xFFFF0000u;
  return x.f;
}
static __device__ __forceinline__ u16 f2bf(float f) {
  union { float f; unsigned int i; } x;
  x.f = f;
  unsigned int i = x.i;
  return (u16)((i + 0x7FFFu + ((i >> 16) & 1u)) >> 16);  // RNE; inputs finite
}
static __device__ __forceinline__ unsigned int pack2(float lo, float hi) {
  return (unsigned int)f2bf(lo) | ((unsigned int)f2bf(hi) << 16);
}

// Stage 1: per-chunk LDS histogram of buckets -> hist row (coalesced write).
__global__ __launch_bounds__(256) void chunk_hist(const int* __restrict__ dst,
                                                  int* __restrict__ hist,
                                                  int E, int Nn, int NB) {
  __shared__ int h[NBP];
  int t = threadIdx.x;
  int c0 = blockIdx.x * CHUNK;
  int end = c0 + CHUNK < E ? c0 + CHUNK : E;
  for (int i = t; i < NB; i += 256) h[i] = 0;
  __syncthreads();
  for (int i = c0 + t; i < end; i += 256) {
    int d = dst[i];
    if ((unsigned)d >= (unsigned)Nn) d = 0;  // defensive
    atomicAdd(&h[d >> SHIFT], 1);
  }
  __syncthreads();
  size_t row = (size_t)blockIdx.x * NBP;
  for (int i = t; i < NB; i += 256) hist[row + i] = h[i];
}

// Stage 2: per-bucket exclusive scan across chunks -> cbbase; totals -> bcnt.
// Block NB additionally decides the mask layout (int32 vs bool).
__global__ __launch_bounds__(256) void col_scan(const int* __restrict__ hist,
                                                int* __restrict__ cbbase,
                                                int* __restrict__ bcnt, int nch,
                                                const unsigned char* __restrict__ m,
                                                int* __restrict__ mflag, int NB) {
  __shared__ int sm[256];
  __shared__ int nzoff;
  int b = blockIdx.x;
  int t = threadIdx.x;
  if (b == NB) {  // fused detect_mask
    if (t == 0) nzoff = 0;
    __syncthreads();
    for (int i = t; i < 4096; i += 256)
      if ((i & 3) && m[i]) atomicAdd(&nzoff, 1);
    __syncthreads();
    if (t == 0) *mflag = (nzoff == 0) ? 1 : 0;  // 1 => int32 layout
    return;
  }
  int carry = 0;
  for (int tile = 0; tile < nch; tile += 256) {
    int c = tile + t;
    int v = (c < nch) ? hist[(size_t)c * NBP + b] : 0;
    sm[t] = v;
    __syncthreads();
    for (int off = 1; off < 256; off <<= 1) {
      int add = (t >= off) ? sm[t - off] : 0;
      __syncthreads();
      sm[t] += add;
      __syncthreads();
    }
    if (c < nch) cbbase[(size_t)c * NBP + b] = carry + sm[t] - v;
    carry += sm[255];
    __syncthreads();
  }
  if (t == 0) bcnt[b] = carry;
}

// Stage 3: LDS counting sort of the chunk, then copy each element to its
// STATIC slot in the bucket-strided pairs array (binary search over base[]).
__global__ __launch_bounds__(256) void chunk_sort_scatter(const int* __restrict__ src,
                                                          const int* __restrict__ dst,
                                                          const int* __restrict__ hist,
                                                          const int* __restrict__ cbbase,
                                                          int* __restrict__ pairs,
                                                          int E, int Nn, int NB) {
  __shared__ int h[NBP];
  __shared__ int base[NBP + 1];
  __shared__ int cur[NBP];
  __shared__ int dp[NBP];  // dp[b] = b*DCAP + cbbase[c][b] - base[b]
  __shared__ int ts[256];
  __shared__ int sorted[CHUNK];
  int t = threadIdx.x;
  int c0 = blockIdx.x * CHUNK;
  int end = c0 + CHUNK < E ? c0 + CHUNK : E;
  int n = end - c0;
  size_t row = (size_t)blockIdx.x * NBP;
  for (int i = t; i < NB; i += 256) h[i] = hist[row + i];
  __syncthreads();
  int v0 = 0, v1 = 0, v2 = 0, v3 = 0, s = 0;
  {
    int b4 = t * 4;
    if (b4 + 0 < NB) { v0 = h[b4 + 0]; s += v0; }
    if (b4 + 1 < NB) { v1 = h[b4 + 1]; s += v1; }
    if (b4 + 2 < NB) { v2 = h[b4 + 2]; s += v2; }
    if (b4 + 3 < NB) { v3 = h[b4 + 3]; s += v3; }
  }
  ts[t] = s;
  __syncthreads();
  for (int off = 1; off < 256; off <<= 1) {
    int add = (t >= off) ? ts[t - off] : 0;
    __syncthreads();
    ts[t] += add;
    __syncthreads();
  }
  {
    int run = t ? ts[t - 1] : 0;
    int b4 = t * 4;
    if (b4 + 0 < NB) { base[b4 + 0] = run; cur[b4 + 0] = run; run += v0; }
    if (b4 + 1 < NB) { base[b4 + 1] = run; cur[b4 + 1] = run; run += v1; }
    if (b4 + 2 < NB) { base[b4 + 2] = run; cur[b4 + 2] = run; run += v2; }
    if (b4 + 3 < NB) { base[b4 + 3] = run; cur[b4 + 3] = run; run += v3; }
  }
  if (t == 0) base[NB] = n;  // sentinel
  __syncthreads();
  for (int i = t; i < NB; i += 256) dp[i] = i * DCAP + cbbase[row + i] - base[i];
  __syncthreads();
  for (int i = c0 + t; i < end; i += 256) {
    int d = dst[i];
    if ((unsigned)d >= (unsigned)Nn) d = 0;
    int sv = src[i];
    if ((unsigned)sv >= (unsigned)Nn) sv = 0;
    int b = d >> SHIFT;
    int r = atomicAdd(&cur[b], 1);
    sorted[r] = ((d & (BNODES - 1)) << 25) | sv;
  }
  __syncthreads();
  for (int i = t; i < n; i += 256) {
    int lo = 0, hi = NB;
    while (hi - lo > 1) {
      int mid = (lo + hi) >> 1;
      if (base[mid] <= i) lo = mid; else hi = mid;
    }
    int p = dp[lo] + i;
    if (p < (lo + 1) * DCAP) pairs[p] = sorted[i];  // capacity guard
  }
}

// Stage 4: one block per bucket. Contiguous pair reads, LDS hist/scan,
// write counts/offs/dinv, scatter to csr region.
__global__ __launch_bounds__(256) void bucket_build(const int* __restrict__ pairs,
                                                    const int* __restrict__ bcnt,
                                                    int* __restrict__ counts,
                                                    int* __restrict__ offs,
                                                    float* __restrict__ dinv,
                                                    int* __restrict__ csr, int Nn) {
  __shared__ int pl[DCAP];
  __shared__ int cl[BNODES], ol[BNODES], cu[BNODES];
  int t = threadIdx.x;
  int b = blockIdx.x;
  int cnt = bcnt[b];
  if (cnt > DCAP) cnt = DCAP;
  int base = b * DCAP;
  for (int i = t; i < cnt; i += 256) pl[i] = pairs[base + i];
  if (t < BNODES) {
    cl[t] = 0;
    cu[t] = 0;
  }
  __syncthreads();
  for (int i = t; i < cnt; i += 256) atomicAdd(&cl[(unsigned)pl[i] >> 25], 1);
  __syncthreads();
  int v = (t < BNODES) ? cl[t] : 0;
  if (t < BNODES) ol[t] = v;
  __syncthreads();
  for (int off = 1; off < BNODES; off <<= 1) {
    int add = (t >= off && t < BNODES) ? ol[t - off] : 0;
    __syncthreads();
    if (t < BNODES) ol[t] += add;
    __syncthreads();
  }
  if (t < BNODES) {
    int excl = ol[t] - v;
    ol[t] = excl;
    int node = (b << SHIFT) + t;
    if (node < Nn) {
      counts[node] = v;
      offs[node] = base + excl;
      dinv[node] = 1.0f / sqrtf((float)(v + 1));  // +1 self-loop
    }
  }
  __syncthreads();
  for (int i = t; i < cnt; i += 256) {
    int p = pl[i];
    int dl = (unsigned)p >> 25;
    int r = atomicAdd(&cu[dl], 1);
    csr[base + ol[dl] + r] = p & 0x1FFFFFF;
  }
}

// out[i][c] = bf16( dinv[i] * sum_k X[i][k]*W[k][c] ), 64x64 tile per block.
template <int K, bool BF_IN>
__global__ __launch_bounds__(256) void gemm_scaled(const void* __restrict__ Xv,
                                                   const float* __restrict__ W,
                                                   const float* __restrict__ dinv,
                                                   u16* __restrict__ out, int nN) {
  __shared__ float xsT[64][68];
  __shared__ float ws[64][68];
  const int t = threadIdx.x;
  const int nbase = blockIdx.x * 64;
  const int gn = t >> 4;
  const int gc = t & 15;
  float acc[4][4] = {};
  for (int kc = 0; kc < K; kc += 64) {
    __syncthreads();
#pragma unroll
    for (int it = 0; it < 4; ++it) {
      int L = it * 256 + t;
      int node = L >> 4;
      int kq = L & 15;
      int n = nbase + node;
      if (n >= nN) n = nN - 1;
      if (BF_IN) {
        const u16* X = (const u16*)Xv;
        ushort4 v = *(const ushort4*)(X + (size_t)n * K + kc + kq * 4);
        xsT[kq * 4 + 0][node] = bf2f(v.x);
        xsT[kq * 4 + 1][node] = bf2f(v.y);
        xsT[kq * 4 + 2][node] = bf2f(v.z);
        xsT[kq * 4 + 3][node] = bf2f(v.w);
      } else {
        const float* X = (const float*)Xv;
        float4 v = *(const float4*)(X + (size_t)n * K + kc + kq * 4);
        xsT[kq * 4 + 0][node] = v.x;
        xsT[kq * 4 + 1][node] = v.y;
        xsT[kq * 4 + 2][node] = v.z;
        xsT[kq * 4 + 3][node] = v.w;
      }
      int wk = L >> 4;
      int wc = (L & 15) * 4;
      float4 wv = *(const float4*)(W + (size_t)(kc + wk) * 64 + wc);
      *(float4*)&ws[wk][wc] = wv;
    }
    __syncthreads();
#pragma unroll
    for (int k = 0; k < 64; ++k) {
      float4 xa = *(const float4*)&xsT[k][gn * 4];
      float4 wa = *(const float4*)&ws[k][gc * 4];
      float xr[4] = {xa.x, xa.y, xa.z, xa.w};
      float wr[4] = {wa.x, wa.y, wa.z, wa.w};
#pragma unroll
      for (int i = 0; i < 4; ++i)
#pragma unroll
        for (int j = 0; j < 4; ++j) acc[i][j] += xr[i] * wr[j];
    }
  }
#pragma unroll
  for (int i = 0; i < 4; ++i) {
    int n = nbase + gn * 4 + i;
    if (n < nN) {
      float s = dinv[n];
      ushort4 o;
      o.x = f2bf(acc[i][0] * s);
      o.y = f2bf(acc[i][1] * s);
      o.z = f2bf(acc[i][2] * s);
      o.w = f2bf(acc[i][3] * s);
      *(ushort4*)(out + (size_t)n * 64 + gc * 4) = o;
    }
  }
}

#define ACC8(vv)                                                               \
  a0 += lo2f(vv.x); a1 += hi2f(vv.x); a2 += lo2f(vv.y); a3 += hi2f(vv.y);      \
  a4 += lo2f(vv.z); a5 += hi2f(vv.z); a6 += lo2f(vv.w); a7 += hi2f(vv.w);

// Gather body: 8 nodes/wave, 8 lanes/node, uint4 (16B = 8 bf16) per lane.
// Per wave-load instruction: 8 edges' rows (1KB) in flight. Produces
// r0..r7 = relu(dinv*acc + bias); leaves nd, ln, l8, dv, alive in scope.
#define GATHER_BODY8(hs)                                                       \
  int wave_l = threadIdx.x >> 6;                                               \
  int lane = threadIdx.x & 63;                                                 \
  int grp = lane >> 3;  /* node slot 0..7 */                                   \
  int l8 = lane & 7;    /* column octet: cols l8*8 .. l8*8+7 */                \
  int ln = wave_l * 8 + grp; /* block-local node 0..31 */                      \
  int node = blockIdx.x * 32 + ln;                                             \
  bool alive = node < nN;                                                      \
  int nd = alive ? node : (nN - 1);                                            \
  int beg = offs[nd];                                                          \
  int c = cnt[nd];                                                             \
  uint4 sv = *(const uint4*)(hs + (size_t)nd * 64 + l8 * 8);                   \
  float a0 = lo2f(sv.x), a1 = hi2f(sv.x), a2 = lo2f(sv.y), a3 = hi2f(sv.y);    \
  float a4 = lo2f(sv.z), a5 = hi2f(sv.z), a6 = lo2f(sv.w), a7 = hi2f(sv.w);    \
  int j = 0;                                                                   \
  for (; j + 4 <= c; j += 4) {                                                 \
    int s0 = csr[beg + j + 0];                                                 \
    int s1 = csr[beg + j + 1];                                                 \
    int s2 = csr[beg + j + 2];                                                 \
    int s3 = csr[beg + j + 3];                                                 \
    uint4 v0 = *(const uint4*)(hs + (size_t)s0 * 64 + l8 * 8);                 \
    uint4 v1 = *(const uint4*)(hs + (size_t)s1 * 64 + l8 * 8);                 \
    uint4 v2 = *(const uint4*)(hs + (size_t)s2 * 64 + l8 * 8);                 \
    uint4 v3 = *(const uint4*)(hs + (size_t)s3 * 64 + l8 * 8);                 \
    ACC8(v0)                                                                   \
    ACC8(v1)                                                                   \
    ACC8(v2)                                                                   \
    ACC8(v3)                                                                   \
  }                                                                            \
  for (; j < c; ++j) {                                                         \
    int s = csr[beg + j];                                                      \
    uint4 v = *(const uint4*)(hs + (size_t)s * 64 + l8 * 8);                   \
    ACC8(v)                                                                    \
  }                                                                            \
  float dv = dinv[nd];                                                         \
  float4 bv0 = *(const float4*)(bias + l8 * 8);                                \
  float4 bv1 = *(const float4*)(bias + l8 * 8 + 4);                            \
  float r0 = dv * a0 + bv0.x;                                                  \
  float r1 = dv * a1 + bv0.y;                                                  \
  float r2 = dv * a2 + bv0.z;                                                  \
  float r3 = dv * a3 + bv0.w;                                                  \
  float r4 = dv * a4 + bv1.x;                                                  \
  float r5 = dv * a5 + bv1.y;                                                  \
  float r6 = dv * a6 + bv1.z;                                                  \
  float r7 = dv * a7 + bv1.w;                                                  \
  r0 = r0 > 0.f ? r0 : 0.f;                                                    \
  r1 = r1 > 0.f ? r1 : 0.f;                                                    \
  r2 = r2 > 0.f ? r2 : 0.f;                                                    \
  r3 = r3 > 0.f ? r3 : 0.f;                                                    \
  r4 = r4 > 0.f ? r4 : 0.f;                                                    \
  r5 = r5 > 0.f ? r5 : 0.f;                                                    \
  r6 = r6 > 0.f ? r6 : 0.f;                                                    \
  r7 = r7 > 0.f ? r7 : 0.f;

// Layer-1 aggregate fused with gemm2 via per-wave LDS row (register-light).
// Same-wave LDS write->read is lockstep-safe: no block barrier after gather.
__global__ __launch_bounds__(256) void aggregate_gemm(const u16* __restrict__ hs1,
                                                      const int* __restrict__ csr,
                                                      const int* __restrict__ offs,
                                                      const int* __restrict__ cnt,
                                                      const float* __restrict__ dinv,
                                                      const float* __restrict__ bias,
                                                      const float* __restrict__ W2,
                                                      u16* __restrict__ hs2, int nN) {
  __shared__ float w2s[64][64];    // [k][col], 16KB
  __shared__ float h1s[32][68];    // per-node row, pad 68
  {
    int t = threadIdx.x;
    for (int i = t; i < 1024; i += 256) {
      float4 wv = *(const float4*)(W2 + (size_t)i * 4);
      *(float4*)&w2s[i >> 4][(i & 15) * 4] = wv;
    }
  }
  __syncthreads();  // weight staging only; all waves arrive together
  GATHER_BODY8(hs1)
  int c8 = l8 * 8;
  float4 st0; st0.x = r0; st0.y = r1; st0.z = r2; st0.w = r3;
  float4 st1; st1.x = r4; st1.y = r5; st1.z = r6; st1.w = r7;
  *(float4*)&h1s[ln][c8] = st0;
  *(float4*)&h1s[ln][c8 + 4] = st1;
  // same-wave readback; compiler inserts lgkmcnt wait
  float o0 = 0.f, o1 = 0.f, o2 = 0.f, o3 = 0.f;
  float o4 = 0.f, o5 = 0.f, o6 = 0.f, o7 = 0.f;
#pragma unroll 4
  for (int k = 0; k < 64; ++k) {
    float hv = h1s[ln][k];                        // broadcast within group
    float4 wa = *(const float4*)&w2s[k][c8];      // 16B
    float4 wb = *(const float4*)&w2s[k][c8 + 4];  // 16B
    o0 += hv * wa.x;
    o1 += hv * wa.y;
    o2 += hv * wa.z;
    o3 += hv * wa.w;
    o4 += hv * wb.x;
    o5 += hv * wb.y;
    o6 += hv * wb.z;
    o7 += hv * wb.w;
  }
  if (alive) {
    uint4 o;
    o.x = pack2(o0 * dv, o1 * dv);
    o.y = pack2(o2 * dv, o3 * dv);
    o.z = pack2(o4 * dv, o5 * dv);
    o.w = pack2(o6 * dv, o7 * dv);
    *(uint4*)(hs2 + (size_t)nd * 64 + c8) = o;
  }
}

// Layer-2 aggregate fused with the head via per-wave LDS row.
// Lane l8 computes logit cols l8 and (l8<2 ? l8+8 : dup).
__global__ __launch_bounds__(256) void aggregate_head(const u16* __restrict__ hs2,
                                                      const int* __restrict__ csr,
                                                      const int* __restrict__ offs,
                                                      const int* __restrict__ cnt,
                                                      const float* __restrict__ dinv,
                                                      const float* __restrict__ bias,
                                                      const float* __restrict__ Wh,
                                                      const float* __restrict__ bh,
                                                      const unsigned char* __restrict__ mask,
                                                      const int* __restrict__ mflag,
                                                      float* __restrict__ out, int nN) {
  __shared__ float whs[640];
  __shared__ float bhs[16];
  __shared__ float h2s[32][68];
  {
    int t = threadIdx.x;
    for (int i = t; i < 640; i += 256) whs[i] = Wh[i];
    if (t < 10) bhs[t] = bh[t];
  }
  __syncthreads();  // staging only
  GATHER_BODY8(hs2)
  int c8 = l8 * 8;
  float4 st0; st0.x = r0; st0.y = r1; st0.z = r2; st0.w = r3;
  float4 st1; st1.x = r4; st1.y = r5; st1.z = r6; st1.w = r7;
  *(float4*)&h2s[ln][c8] = st0;
  *(float4*)&h2s[ln][c8 + 4] = st1;
  // two logits per lane (cols l8 and l8+8; clamp dup for l8>=2)
  int cc0 = l8;
  int cc1 = (l8 + 8 < 10) ? (l8 + 8) : 9;
  float acc0 = bhs[cc0];
  float acc1 = bhs[cc1];
#pragma unroll 4
  for (int k = 0; k < 64; ++k) {
    float hv = h2s[ln][k];
    acc0 += hv * whs[k * 10 + cc0];
    acc1 += hv * whs[k * 10 + cc1];
  }
  if (alive) {
    size_t idx0 = (size_t)nd * 10 + cc0;
    bool mv0 = (*mflag) ? (((const int*)mask)[idx0] != 0) : (mask[idx0] != 0);
    out[idx0] = mv0 ? acc0 : MASKED_VAL;
    if (l8 < 2) {
      size_t idx1 = (size_t)nd * 10 + cc1;
      bool mv1 = (*mflag) ? (((const int*)mask)[idx1] != 0) : (mask[idx1] != 0);
      out[idx1] = mv1 ? acc1 : MASKED_VAL;
    }
  }
}

extern "C" void kernel_launch(void* const* d_in, const int* in_sizes, int n_in,
                              void* d_out, int out_size, void* d_ws, size_t ws_size,
                              hipStream_t stream) {
  const float* x = (const float*)d_in[0];
  const int* ei = (const int*)d_in[1];  // int32
  const unsigned char* mask = (const unsigned char*)d_in[2];
  const float* W1 = (const float*)d_in[3];
  const float* b1 = (const float*)d_in[4];
  const float* W2 = (const float*)d_in[5];
  const float* b2 = (const float*)d_in[6];
  const float* Wh = (const float*)d_in[7];
  const float* bh = (const float*)d_in[8];
  float* out = (float*)d_out;

  const int N = in_sizes[0] / 128;
  const int E = in_sizes[1] / 2;
  const int* src = ei;
  const int* dst = ei + E;
  const int NB = (N + BNODES - 1) >> SHIFT;     // 782 buckets
  const int nchunks = (E + CHUNK - 1) / CHUNK;  // 782 chunks at CHUNK=4096

  // workspace (~60MB): pairs region aliases bufB (pairs dies in bucket_build;
  // bufB is first written by aggregate_gemm afterwards).
  char* w = (char*)d_ws;
  auto alloc = [&](size_t bytes) {
    void* p = (void*)w;
    w += (bytes + 255) / 256 * 256;
    return p;
  };
  int* counts = (int*)alloc((size_t)N * 4);
  int* offs = (int*)alloc((size_t)N * 4);
  float* dinv = (float*)alloc((size_t)N * 4);
  int* bcnt = (int*)alloc(1024 * 4);
  int* mflag = (int*)alloc(4);
  int* hist = (int*)alloc((size_t)nchunks * NBP * 4);
  int* cbbase = (int*)alloc((size_t)nchunks * NBP * 4);
  int* csr = (int*)alloc((size_t)NB * DCAP * 4);
  u16* bufA = (u16*)alloc((size_t)N * 64 * 2);
  size_t pairs_bytes = (size_t)NB * DCAP * 4;
  size_t bufB_bytes = (size_t)N * 64 * 2;
  void* shared_raw = alloc(pairs_bytes > bufB_bytes ? pairs_bytes : bufB_bytes);
  u16* bufB = (u16*)shared_raw;
  int* pairs = (int*)shared_raw;

  const int ablocks = (N + 31) / 32;

  chunk_hist<<<nchunks, 256, 0, stream>>>(dst, hist, E, N, NB);
  col_scan<<<NB + 1, 256, 0, stream>>>(hist, cbbase, bcnt, nchunks, mask, mflag, NB);
  chunk_sort_scatter<<<nchunks, 256, 0, stream>>>(src, dst, hist, cbbase,
                                                  pairs, E, N, NB);
  bucket_build<<<NB, 256, 0, stream>>>(pairs, bcnt, counts, offs, dinv, csr, N);

  gemm_scaled<128, false><<<(N + 63) / 64, 256, 0, stream>>>(x, W1, dinv, bufA, N);
  aggregate_gemm<<<ablocks, 256, 0, stream>>>(bufA, csr, offs, counts, dinv, b1,
                                              W2, bufB, N);
  aggregate_head<<<ablocks, 256, 0, stream>>>(bufB, csr, offs, counts, dinv, b2,
                                              Wh, bh, mask, mflag, out, N);
}

// Round 17
// 224.332 us; speedup vs baseline: 1.0083x; 1.0083x over previous
//
#include <hip/hip_runtime.h>
#include <float.h>
#include <math.h>

// ---------------------------------------------------------------------------
// GCN forward, bf16 intermediates, fused register-light tails (R15 structure,
// the measured optimum):
//   hs1 = dinv*(x W1) [bf16, gemm1]
//   agg_gemm: h1 = relu(dinv*S(hs1)+b1) -> per-wave LDS -> hs2 = dinv*(h1 W2)
//   agg_head: h2 = relu(dinv*S(hs2)+b2) -> per-wave LDS -> logits -> mask
// Ahat = D^-1/2 (A+I) D^-1/2.  CSR by scan-based counting sort (atomic-free).
// Established facts:
//   - edge_index int32, d_out float32, masked slots need bf16-finite value
//     (-3.3895e38 = bf16 0xFF7F; expected's -3.4028e38 is -inf in bf16).
//   - R4 atomics / R7 random 4B writes / R8 run regather: all bad.
//   - R9/R10: gather at random-128B fabric ceiling only at high occupancy.
//   - R12: VGPR>64 halves waves/SIMD -> gather BW collapses.
//   - R13/R15 (224us best): per-wave LDS tails, 36 VGPR, CHUNK=4096.
//   - R14 REGRESSED: bf16-W2 tail (VALU cvt) + perm indirection (locality).
//   - R16 REGRESSED: 8-lane/uint4 gather (FETCH +10MB, bank conflicts,
//     LDS-occupancy loss; VALU unchanged) -> 16-lane gather is optimal.
//   - Fused aggregates are pinned at ~70us across every variant tried:
//     this is the random-128B-row LLC-gather ceiling at ~62% occupancy.
// ---------------------------------------------------------------------------

#define MASKED_VAL (-3.3895313892515355e+38f)
#define SHIFT 7
#define BNODES 128   // 1<<SHIFT nodes per bucket
#define CHUNK 4096   // edges per chunk
#define DCAP 6144    // per-bucket region capacity (mean 4096, >30 sigma)
#define NBP 800      // padded row stride for hist/cbbase matrices

typedef unsigned short u16;

static __device__ __forceinline__ float bf2f(u16 u) {
  union { unsigned int i; float f; } x;
  x.i = ((unsigned int)u) << 16;
  return x.f;
}
static __device__ __forceinline__ u16 f2bf(float f) {
  union { float f; unsigned int i; } x;
  x.f = f;
  unsigned int i = x.i;
  return (u16)((i + 0x7FFFu + ((i >> 16) & 1u)) >> 16);  // RNE; inputs finite
}

// Stage 1: per-chunk LDS histogram of buckets -> hist row (coalesced write).
__global__ __launch_bounds__(256) void chunk_hist(const int* __restrict__ dst,
                                                  int* __restrict__ hist,
                                                  int E, int Nn, int NB) {
  __shared__ int h[NBP];
  int t = threadIdx.x;
  int c0 = blockIdx.x * CHUNK;
  int end = c0 + CHUNK < E ? c0 + CHUNK : E;
  for (int i = t; i < NB; i += 256) h[i] = 0;
  __syncthreads();
  for (int i = c0 + t; i < end; i += 256) {
    int d = dst[i];
    if ((unsigned)d >= (unsigned)Nn) d = 0;  // defensive
    atomicAdd(&h[d >> SHIFT], 1);
  }
  __syncthreads();
  size_t row = (size_t)blockIdx.x * NBP;
  for (int i = t; i < NB; i += 256) hist[row + i] = h[i];
}

// Stage 2: per-bucket exclusive scan across chunks -> cbbase; totals -> bcnt.
// Block NB additionally decides the mask layout (int32 vs bool).
__global__ __launch_bounds__(256) void col_scan(const int* __restrict__ hist,
                                                int* __restrict__ cbbase,
                                                int* __restrict__ bcnt, int nch,
                                                const unsigned char* __restrict__ m,
                                                int* __restrict__ mflag, int NB) {
  __shared__ int sm[256];
  __shared__ int nzoff;
  int b = blockIdx.x;
  int t = threadIdx.x;
  if (b == NB) {  // fused detect_mask
    if (t == 0) nzoff = 0;
    __syncthreads();
    for (int i = t; i < 4096; i += 256)
      if ((i & 3) && m[i]) atomicAdd(&nzoff, 1);
    __syncthreads();
    if (t == 0) *mflag = (nzoff == 0) ? 1 : 0;  // 1 => int32 layout
    return;
  }
  int carry = 0;
  for (int tile = 0; tile < nch; tile += 256) {
    int c = tile + t;
    int v = (c < nch) ? hist[(size_t)c * NBP + b] : 0;
    sm[t] = v;
    __syncthreads();
    for (int off = 1; off < 256; off <<= 1) {
      int add = (t >= off) ? sm[t - off] : 0;
      __syncthreads();
      sm[t] += add;
      __syncthreads();
    }
    if (c < nch) cbbase[(size_t)c * NBP + b] = carry + sm[t] - v;
    carry += sm[255];
    __syncthreads();
  }
  if (t == 0) bcnt[b] = carry;
}

// Stage 3: LDS counting sort of the chunk, then copy each element to its
// STATIC slot in the bucket-strided pairs array (binary search over base[]).
__global__ __launch_bounds__(256) void chunk_sort_scatter(const int* __restrict__ src,
                                                          const int* __restrict__ dst,
                                                          const int* __restrict__ hist,
                                                          const int* __restrict__ cbbase,
                                                          int* __restrict__ pairs,
                                                          int E, int Nn, int NB) {
  __shared__ int h[NBP];
  __shared__ int base[NBP + 1];
  __shared__ int cur[NBP];
  __shared__ int dp[NBP];  // dp[b] = b*DCAP + cbbase[c][b] - base[b]
  __shared__ int ts[256];
  __shared__ int sorted[CHUNK];
  int t = threadIdx.x;
  int c0 = blockIdx.x * CHUNK;
  int end = c0 + CHUNK < E ? c0 + CHUNK : E;
  int n = end - c0;
  size_t row = (size_t)blockIdx.x * NBP;
  for (int i = t; i < NB; i += 256) h[i] = hist[row + i];
  __syncthreads();
  int v0 = 0, v1 = 0, v2 = 0, v3 = 0, s = 0;
  {
    int b4 = t * 4;
    if (b4 + 0 < NB) { v0 = h[b4 + 0]; s += v0; }
    if (b4 + 1 < NB) { v1 = h[b4 + 1]; s += v1; }
    if (b4 + 2 < NB) { v2 = h[b4 + 2]; s += v2; }
    if (b4 + 3 < NB) { v3 = h[b4 + 3]; s += v3; }
  }
  ts[t] = s;
  __syncthreads();
  for (int off = 1; off < 256; off <<= 1) {
    int add = (t >= off) ? ts[t - off] : 0;
    __syncthreads();
    ts[t] += add;
    __syncthreads();
  }
  {
    int run = t ? ts[t - 1] : 0;
    int b4 = t * 4;
    if (b4 + 0 < NB) { base[b4 + 0] = run; cur[b4 + 0] = run; run += v0; }
    if (b4 + 1 < NB) { base[b4 + 1] = run; cur[b4 + 1] = run; run += v1; }
    if (b4 + 2 < NB) { base[b4 + 2] = run; cur[b4 + 2] = run; run += v2; }
    if (b4 + 3 < NB) { base[b4 + 3] = run; cur[b4 + 3] = run; run += v3; }
  }
  if (t == 0) base[NB] = n;  // sentinel
  __syncthreads();
  for (int i = t; i < NB; i += 256) dp[i] = i * DCAP + cbbase[row + i] - base[i];
  __syncthreads();
  for (int i = c0 + t; i < end; i += 256) {
    int d = dst[i];
    if ((unsigned)d >= (unsigned)Nn) d = 0;
    int sv = src[i];
    if ((unsigned)sv >= (unsigned)Nn) sv = 0;
    int b = d >> SHIFT;
    int r = atomicAdd(&cur[b], 1);
    sorted[r] = ((d & (BNODES - 1)) << 25) | sv;
  }
  __syncthreads();
  for (int i = t; i < n; i += 256) {
    int lo = 0, hi = NB;
    while (hi - lo > 1) {
      int mid = (lo + hi) >> 1;
      if (base[mid] <= i) lo = mid; else hi = mid;
    }
    int p = dp[lo] + i;
    if (p < (lo + 1) * DCAP) pairs[p] = sorted[i];  // capacity guard
  }
}

// Stage 4: one block per bucket. Contiguous pair reads, LDS hist/scan,
// write counts/offs/dinv, scatter to csr region.
__global__ __launch_bounds__(256) void bucket_build(const int* __restrict__ pairs,
                                                    const int* __restrict__ bcnt,
                                                    int* __restrict__ counts,
                                                    int* __restrict__ offs,
                                                    float* __restrict__ dinv,
                                                    int* __restrict__ csr, int Nn) {
  __shared__ int pl[DCAP];
  __shared__ int cl[BNODES], ol[BNODES], cu[BNODES];
  int t = threadIdx.x;
  int b = blockIdx.x;
  int cnt = bcnt[b];
  if (cnt > DCAP) cnt = DCAP;
  int base = b * DCAP;
  for (int i = t; i < cnt; i += 256) pl[i] = pairs[base + i];
  if (t < BNODES) {
    cl[t] = 0;
    cu[t] = 0;
  }
  __syncthreads();
  for (int i = t; i < cnt; i += 256) atomicAdd(&cl[(unsigned)pl[i] >> 25], 1);
  __syncthreads();
  int v = (t < BNODES) ? cl[t] : 0;
  if (t < BNODES) ol[t] = v;
  __syncthreads();
  for (int off = 1; off < BNODES; off <<= 1) {
    int add = (t >= off && t < BNODES) ? ol[t - off] : 0;
    __syncthreads();
    if (t < BNODES) ol[t] += add;
    __syncthreads();
  }
  if (t < BNODES) {
    int excl = ol[t] - v;
    ol[t] = excl;
    int node = (b << SHIFT) + t;
    if (node < Nn) {
      counts[node] = v;
      offs[node] = base + excl;
      dinv[node] = 1.0f / sqrtf((float)(v + 1));  // +1 self-loop
    }
  }
  __syncthreads();
  for (int i = t; i < cnt; i += 256) {
    int p = pl[i];
    int dl = (unsigned)p >> 25;
    int r = atomicAdd(&cu[dl], 1);
    csr[base + ol[dl] + r] = p & 0x1FFFFFF;
  }
}

// out[i][c] = bf16( dinv[i] * sum_k X[i][k]*W[k][c] ), 64x64 tile per block.
template <int K, bool BF_IN>
__global__ __launch_bounds__(256) void gemm_scaled(const void* __restrict__ Xv,
                                                   const float* __restrict__ W,
                                                   const float* __restrict__ dinv,
                                                   u16* __restrict__ out, int nN) {
  __shared__ float xsT[64][68];
  __shared__ float ws[64][68];
  const int t = threadIdx.x;
  const int nbase = blockIdx.x * 64;
  const int gn = t >> 4;
  const int gc = t & 15;
  float acc[4][4] = {};
  for (int kc = 0; kc < K; kc += 64) {
    __syncthreads();
#pragma unroll
    for (int it = 0; it < 4; ++it) {
      int L = it * 256 + t;
      int node = L >> 4;
      int kq = L & 15;
      int n = nbase + node;
      if (n >= nN) n = nN - 1;
      if (BF_IN) {
        const u16* X = (const u16*)Xv;
        ushort4 v = *(const ushort4*)(X + (size_t)n * K + kc + kq * 4);
        xsT[kq * 4 + 0][node] = bf2f(v.x);
        xsT[kq * 4 + 1][node] = bf2f(v.y);
        xsT[kq * 4 + 2][node] = bf2f(v.z);
        xsT[kq * 4 + 3][node] = bf2f(v.w);
      } else {
        const float* X = (const float*)Xv;
        float4 v = *(const float4*)(X + (size_t)n * K + kc + kq * 4);
        xsT[kq * 4 + 0][node] = v.x;
        xsT[kq * 4 + 1][node] = v.y;
        xsT[kq * 4 + 2][node] = v.z;
        xsT[kq * 4 + 3][node] = v.w;
      }
      int wk = L >> 4;
      int wc = (L & 15) * 4;
      float4 wv = *(const float4*)(W + (size_t)(kc + wk) * 64 + wc);
      *(float4*)&ws[wk][wc] = wv;
    }
    __syncthreads();
#pragma unroll
    for (int k = 0; k < 64; ++k) {
      float4 xa = *(const float4*)&xsT[k][gn * 4];
      float4 wa = *(const float4*)&ws[k][gc * 4];
      float xr[4] = {xa.x, xa.y, xa.z, xa.w};
      float wr[4] = {wa.x, wa.y, wa.z, wa.w};
#pragma unroll
      for (int i = 0; i < 4; ++i)
#pragma unroll
        for (int j = 0; j < 4; ++j) acc[i][j] += xr[i] * wr[j];
    }
  }
#pragma unroll
  for (int i = 0; i < 4; ++i) {
    int n = nbase + gn * 4 + i;
    if (n < nN) {
      float s = dinv[n];
      ushort4 o;
      o.x = f2bf(acc[i][0] * s);
      o.y = f2bf(acc[i][1] * s);
      o.z = f2bf(acc[i][2] * s);
      o.w = f2bf(acc[i][3] * s);
      *(ushort4*)(out + (size_t)n * 64 + gc * 4) = o;
    }
  }
}

// Shared gather body: 4 nodes/wave, 16 lanes/node, ushort4/lane, unroll-8
// dual accumulators (proven optimal R10/R15). Produces r0..r3 =
// relu(dinv*acc + bias); leaves nd, ln, l16, dv, alive in scope.
#define GATHER_BODY(hs)                                                        \
  int wave_l = threadIdx.x >> 6;                                               \
  int lane = threadIdx.x & 63;                                                 \
  int sub = lane >> 4;                                                         \
  int l16 = lane & 15;                                                         \
  int ln = wave_l * 4 + sub; /* block-local node 0..15 */                      \
  int node = blockIdx.x * 16 + ln;                                             \
  bool alive = node < nN;                                                      \
  int nd = alive ? node : (nN - 1);                                            \
  int beg = offs[nd];                                                          \
  int c = cnt[nd];                                                             \
  ushort4 sv = *(const ushort4*)(hs + (size_t)nd * 64 + l16 * 4);              \
  float a0 = bf2f(sv.x), a1 = bf2f(sv.y), a2 = bf2f(sv.z), a3 = bf2f(sv.w);    \
  float b0 = 0.f, b1 = 0.f, b2 = 0.f, b3 = 0.f;                                \
  int j = 0;                                                                   \
  for (; j + 8 <= c; j += 8) {                                                 \
    int s0 = csr[beg + j + 0];                                                 \
    int s1 = csr[beg + j + 1];                                                 \
    int s2 = csr[beg + j + 2];                                                 \
    int s3 = csr[beg + j + 3];                                                 \
    int s4 = csr[beg + j + 4];                                                 \
    int s5 = csr[beg + j + 5];                                                 \
    int s6 = csr[beg + j + 6];                                                 \
    int s7 = csr[beg + j + 7];                                                 \
    ushort4 v0 = *(const ushort4*)(hs + (size_t)s0 * 64 + l16 * 4);            \
    ushort4 v1 = *(const ushort4*)(hs + (size_t)s1 * 64 + l16 * 4);            \
    ushort4 v2 = *(const ushort4*)(hs + (size_t)s2 * 64 + l16 * 4);            \
    ushort4 v3 = *(const ushort4*)(hs + (size_t)s3 * 64 + l16 * 4);            \
    ushort4 v4 = *(const ushort4*)(hs + (size_t)s4 * 64 + l16 * 4);            \
    ushort4 v5 = *(const ushort4*)(hs + (size_t)s5 * 64 + l16 * 4);            \
    ushort4 v6 = *(const ushort4*)(hs + (size_t)s6 * 64 + l16 * 4);            \
    ushort4 v7 = *(const ushort4*)(hs + (size_t)s7 * 64 + l16 * 4);            \
    a0 += bf2f(v0.x); a1 += bf2f(v0.y); a2 += bf2f(v0.z); a3 += bf2f(v0.w);    \
    b0 += bf2f(v1.x); b1 += bf2f(v1.y); b2 += bf2f(v1.z); b3 += bf2f(v1.w);    \
    a0 += bf2f(v2.x); a1 += bf2f(v2.y); a2 += bf2f(v2.z); a3 += bf2f(v2.w);    \
    b0 += bf2f(v3.x); b1 += bf2f(v3.y); b2 += bf2f(v3.z); b3 += bf2f(v3.w);    \
    a0 += bf2f(v4.x); a1 += bf2f(v4.y); a2 += bf2f(v4.z); a3 += bf2f(v4.w);    \
    b0 += bf2f(v5.x); b1 += bf2f(v5.y); b2 += bf2f(v5.z); b3 += bf2f(v5.w);    \
    a0 += bf2f(v6.x); a1 += bf2f(v6.y); a2 += bf2f(v6.z); a3 += bf2f(v6.w);    \
    b0 += bf2f(v7.x); b1 += bf2f(v7.y); b2 += bf2f(v7.z); b3 += bf2f(v7.w);    \
  }                                                                            \
  for (; j < c; ++j) {                                                         \
    int s = csr[beg + j];                                                      \
    ushort4 v = *(const ushort4*)(hs + (size_t)s * 64 + l16 * 4);              \
    a0 += bf2f(v.x); a1 += bf2f(v.y); a2 += bf2f(v.z); a3 += bf2f(v.w);        \
  }                                                                            \
  a0 += b0; a1 += b1; a2 += b2; a3 += b3;                                      \
  float dv = dinv[nd];                                                         \
  float4 bv = *(const float4*)(bias + l16 * 4);                                \
  float r0 = dv * a0 + bv.x;                                                   \
  float r1 = dv * a1 + bv.y;                                                   \
  float r2 = dv * a2 + bv.z;                                                   \
  float r3 = dv * a3 + bv.w;                                                   \
  r0 = r0 > 0.f ? r0 : 0.f;                                                    \
  r1 = r1 > 0.f ? r1 : 0.f;                                                    \
  r2 = r2 > 0.f ? r2 : 0.f;                                                    \
  r3 = r3 > 0.f ? r3 : 0.f;

// Layer-1 aggregate fused with gemm2 via per-wave LDS row (register-light).
// Same-wave LDS write->read is lockstep-safe: no block barrier after gather.
__global__ __launch_bounds__(256) void aggregate_gemm(const u16* __restrict__ hs1,
                                                      const int* __restrict__ csr,
                                                      const int* __restrict__ offs,
                                                      const int* __restrict__ cnt,
                                                      const float* __restrict__ dinv,
                                                      const float* __restrict__ bias,
                                                      const float* __restrict__ W2,
                                                      u16* __restrict__ hs2, int nN) {
  __shared__ float w2s[64][64];    // [k][col], 16KB; 64-float rows: 2-way free
  __shared__ float h1s[16][68];    // per-node row, pad 68 breaks bank overlap
  {
    int t = threadIdx.x;
    for (int i = t; i < 1024; i += 256) {
      float4 wv = *(const float4*)(W2 + (size_t)i * 4);
      *(float4*)&w2s[i >> 4][(i & 15) * 4] = wv;
    }
  }
  __syncthreads();  // weight staging only; all waves arrive together
  GATHER_BODY(hs1)
  int c4 = l16 * 4;
  h1s[ln][c4 + 0] = r0;
  h1s[ln][c4 + 1] = r1;
  h1s[ln][c4 + 2] = r2;
  h1s[ln][c4 + 3] = r3;
  // same-wave readback; compiler inserts lgkmcnt wait
  float o0 = 0.f, o1 = 0.f, o2 = 0.f, o3 = 0.f;
#pragma unroll 4
  for (int k = 0; k < 64; ++k) {
    float hv = h1s[ln][k];                       // broadcast within group
    float4 wr = *(const float4*)&w2s[k][c4];     // 16B aligned
    o0 += hv * wr.x;
    o1 += hv * wr.y;
    o2 += hv * wr.z;
    o3 += hv * wr.w;
  }
  if (alive) {
    ushort4 o;
    o.x = f2bf(o0 * dv);
    o.y = f2bf(o1 * dv);
    o.z = f2bf(o2 * dv);
    o.w = f2bf(o3 * dv);
    *(ushort4*)(hs2 + (size_t)nd * 64 + c4) = o;
  }
}

// Layer-2 aggregate fused with the head via per-wave LDS row.
__global__ __launch_bounds__(256) void aggregate_head(const u16* __restrict__ hs2,
                                                      const int* __restrict__ csr,
                                                      const int* __restrict__ offs,
                                                      const int* __restrict__ cnt,
                                                      const float* __restrict__ dinv,
                                                      const float* __restrict__ bias,
                                                      const float* __restrict__ Wh,
                                                      const float* __restrict__ bh,
                                                      const unsigned char* __restrict__ mask,
                                                      const int* __restrict__ mflag,
                                                      float* __restrict__ out, int nN) {
  __shared__ float whs[640];
  __shared__ float bhs[16];
  __shared__ float h2s[16][68];
  {
    int t = threadIdx.x;
    for (int i = t; i < 640; i += 256) whs[i] = Wh[i];
    if (t < 10) bhs[t] = bh[t];
  }
  __syncthreads();  // staging only
  GATHER_BODY(hs2)
  int c4 = l16 * 4;
  h2s[ln][c4 + 0] = r0;
  h2s[ln][c4 + 1] = r1;
  h2s[ln][c4 + 2] = r2;
  h2s[ln][c4 + 3] = r3;
  // lanes l16<10 compute one logit each for node nd (same-wave readback)
  if (alive && l16 < 10) {
    float acc = bhs[l16];
#pragma unroll 4
    for (int k = 0; k < 64; ++k) acc += h2s[ln][k] * whs[k * 10 + l16];
    size_t idx = (size_t)nd * 10 + l16;
    bool mv = (*mflag) ? (((const int*)mask)[idx] != 0) : (mask[idx] != 0);
    out[idx] = mv ? acc : MASKED_VAL;
  }
}

extern "C" void kernel_launch(void* const* d_in, const int* in_sizes, int n_in,
                              void* d_out, int out_size, void* d_ws, size_t ws_size,
                              hipStream_t stream) {
  const float* x = (const float*)d_in[0];
  const int* ei = (const int*)d_in[1];  // int32
  const unsigned char* mask = (const unsigned char*)d_in[2];
  const float* W1 = (const float*)d_in[3];
  const float* b1 = (const float*)d_in[4];
  const float* W2 = (const float*)d_in[5];
  const float* b2 = (const float*)d_in[6];
  const float* Wh = (const float*)d_in[7];
  const float* bh = (const float*)d_in[8];
  float* out = (float*)d_out;

  const int N = in_sizes[0] / 128;
  const int E = in_sizes[1] / 2;
  const int* src = ei;
  const int* dst = ei + E;
  const int NB = (N + BNODES - 1) >> SHIFT;     // 782 buckets
  const int nchunks = (E + CHUNK - 1) / CHUNK;  // 782 chunks at CHUNK=4096

  // workspace (~60MB): pairs region aliases bufB (pairs dies in bucket_build;
  // bufB is first written by aggregate_gemm afterwards).
  char* w = (char*)d_ws;
  auto alloc = [&](size_t bytes) {
    void* p = (void*)w;
    w += (bytes + 255) / 256 * 256;
    return p;
  };
  int* counts = (int*)alloc((size_t)N * 4);
  int* offs = (int*)alloc((size_t)N * 4);
  float* dinv = (float*)alloc((size_t)N * 4);
  int* bcnt = (int*)alloc(1024 * 4);
  int* mflag = (int*)alloc(4);
  int* hist = (int*)alloc((size_t)nchunks * NBP * 4);
  int* cbbase = (int*)alloc((size_t)nchunks * NBP * 4);
  int* csr = (int*)alloc((size_t)NB * DCAP * 4);
  u16* bufA = (u16*)alloc((size_t)N * 64 * 2);
  size_t pairs_bytes = (size_t)NB * DCAP * 4;
  size_t bufB_bytes = (size_t)N * 64 * 2;
  void* shared_raw = alloc(pairs_bytes > bufB_bytes ? pairs_bytes : bufB_bytes);
  u16* bufB = (u16*)shared_raw;
  int* pairs = (int*)shared_raw;

  const int ablocks = (N + 15) / 16;

  chunk_hist<<<nchunks, 256, 0, stream>>>(dst, hist, E, N, NB);
  col_scan<<<NB + 1, 256, 0, stream>>>(hist, cbbase, bcnt, nchunks, mask, mflag, NB);
  chunk_sort_scatter<<<nchunks, 256, 0, stream>>>(src, dst, hist, cbbase,
                                                  pairs, E, N, NB);
  bucket_build<<<NB, 256, 0, stream>>>(pairs, bcnt, counts, offs, dinv, csr, N);

  gemm_scaled<128, false><<<(N + 63) / 64, 256, 0, stream>>>(x, W1, dinv, bufA, N);
  aggregate_gemm<<<ablocks, 256, 0, stream>>>(bufA, csr, offs, counts, dinv, b1,
                                              W2, bufB, N);
  aggregate_head<<<ablocks, 256, 0, stream>>>(bufB, csr, offs, counts, dinv, b2,
                                              Wh, bh, mask, mflag, out, N);
}